// Round 1
// baseline (491.325 us; speedup 1.0000x reference)
//
#include <hip/hip_runtime.h>

#define NROWS 65536
#define NCAT 16
#define BCAT 32   // blocks per category in k_main

__constant__ int c_shift[NCAT] = {0,4,6,8,12,16,19,22,24,28,34,36,42,45,48,51};
__constant__ int c_len[NCAT]   = {4,2,2,4,4,3,3,2,4,6,2,6,3,3,3,3};

// ---------------------------------------------------------------------------
// K1: partial Gram matrix G = F^T F (atomicAdd), column sums, label histogram
// 256 blocks x 256 threads; block handles 256 rows; thread owns an 8x8 G tile.
// ---------------------------------------------------------------------------
__global__ __launch_bounds__(256) void k_stats(
    const float* __restrict__ F, const int* __restrict__ lab,
    float* __restrict__ G, float* __restrict__ sv, int* __restrict__ counts)
{
  __shared__ float ft[16][132];   // +4 pad: cheap bank spread, keeps 16B align
  __shared__ int hl[NCAT];
  const int tid = threadIdx.x;
  if (tid < NCAT) hl[tid] = 0;
  __syncthreads();
  const int rowbase = blockIdx.x * 256;
  atomicAdd(&hl[lab[rowbase + tid]], 1);

  float acc[8][8];
  #pragma unroll
  for (int a = 0; a < 8; ++a)
    #pragma unroll
    for (int b = 0; b < 8; ++b) acc[a][b] = 0.f;
  float cs = 0.f;
  const int ty = tid >> 4, tx = tid & 15;
  const int r = tid >> 4;          // staging row 0..15
  const int c0 = (tid & 15) * 8;   // staging col

  for (int t = 0; t < 16; ++t) {
    __syncthreads();
    const float* src = F + ((size_t)(rowbase + t * 16 + r)) * 128 + c0;
    float4 a0 = *(const float4*)src;
    float4 a1 = *(const float4*)(src + 4);
    *(float4*)&ft[r][c0]     = a0;
    *(float4*)&ft[r][c0 + 4] = a1;
    __syncthreads();
    #pragma unroll 2
    for (int rr = 0; rr < 16; ++rr) {
      float fa[8], fb[8];
      *(float4*)&fa[0] = *(const float4*)&ft[rr][ty * 8];
      *(float4*)&fa[4] = *(const float4*)&ft[rr][ty * 8 + 4];
      *(float4*)&fb[0] = *(const float4*)&ft[rr][tx * 8];
      *(float4*)&fb[4] = *(const float4*)&ft[rr][tx * 8 + 4];
      #pragma unroll
      for (int a = 0; a < 8; ++a)
        #pragma unroll
        for (int b = 0; b < 8; ++b)
          acc[a][b] = fmaf(fa[a], fb[b], acc[a][b]);
    }
    if (tid < 128) {
      #pragma unroll
      for (int rr = 0; rr < 16; ++rr) cs += ft[rr][tid];
    }
  }
  if (tid < 128) atomicAdd(&sv[tid], cs);
  if (tid < NCAT) atomicAdd(&counts[tid], hl[tid]);
  #pragma unroll
  for (int a = 0; a < 8; ++a)
    #pragma unroll
    for (int b = 0; b < 8; ++b)
      atomicAdd(&G[(ty * 8 + a) * 128 + tx * 8 + b], acc[a][b]);
}

// ---------------------------------------------------------------------------
// K2: BN parameters. var_j = w_j^T G w_j / N - mean_j^2 ; scale/shift.
// 128 blocks x 256 threads; block = 16 columns x 16 i-range parts.
// ---------------------------------------------------------------------------
__global__ __launch_bounds__(256) void k_params(
    const float* __restrict__ G, const float* __restrict__ sv,
    const float* __restrict__ W1, const float* __restrict__ gamma,
    const float* __restrict__ beta, float* __restrict__ scale,
    float* __restrict__ shiftv)
{
  __shared__ float Gl[128][133];  // pad 133: parts (i step 8) land on distinct banks
  __shared__ float Wl[128][16];
  __shared__ float redq[16][16];
  __shared__ float redm[16][16];
  const int tid = threadIdx.x;
  const int jb = blockIdx.x * 16;
  for (int i = tid; i < 16384; i += 256) Gl[i >> 7][i & 127] = G[i];
  for (int i = tid; i < 2048; i += 256) {
    int k = i >> 4, col = i & 15;
    Wl[k][col] = W1[(size_t)k * 2048 + jb + col];
  }
  __syncthreads();
  const int col = tid & 15, part = tid >> 4;   // part: i-range of 8
  float msq = 0.f, mean = 0.f;
  for (int ii = 0; ii < 8; ++ii) {
    const int i = part * 8 + ii;
    const float wi = Wl[i][col];
    float inner = 0.f;
    #pragma unroll 8
    for (int k = 0; k < 128; ++k) inner = fmaf(Gl[i][k], Wl[k][col], inner);
    msq = fmaf(wi, inner, msq);
  }
  #pragma unroll
  for (int kk = 0; kk < 8; ++kk) {
    const int k = part * 8 + kk;
    mean = fmaf(sv[k], Wl[k][col], mean);
  }
  redq[part][col] = msq;
  redm[part][col] = mean;
  __syncthreads();
  if (tid < 16) {
    float q = 0.f, m = 0.f;
    #pragma unroll
    for (int p = 0; p < 16; ++p) { q += redq[p][tid]; m += redm[p][tid]; }
    m *= (1.f / 65536.f);
    q *= (1.f / 65536.f);
    float var = q - m * m;
    float sc = gamma[jb + tid] * rsqrtf(var + 1e-5f);
    scale[jb + tid] = sc;
    shiftv[jb + tid] = beta[jb + tid] - m * sc;
  }
}

// ---------------------------------------------------------------------------
// K3: compact row indices by category (wave-aggregated atomics).
// ---------------------------------------------------------------------------
__global__ __launch_bounds__(256) void k_scatter(
    const int* __restrict__ lab, const int* __restrict__ counts,
    int* __restrict__ cursors, int* __restrict__ rowidx)
{
  const int n = blockIdx.x * 256 + threadIdx.x;
  const int c = lab[n];
  int off = 0;
  #pragma unroll
  for (int t = 0; t < NCAT; ++t) off += (t < c) ? counts[t] : 0;
  const int lane = threadIdx.x & 63;
  const unsigned long long lanebit = 1ull << lane;
  for (int cc = 0; cc < NCAT; ++cc) {
    unsigned long long m = __ballot(c == cc);
    if (c == cc) {
      int rank = (int)__popcll(m & (lanebit - 1));
      int leader = __ffsll((unsigned long long)m) - 1;
      int base = 0;
      if (lane == leader) base = atomicAdd(&cursors[cc], (int)__popcll(m));
      base = __shfl(base, leader);
      rowidx[off + base + rank] = n;
    }
  }
}

// ---------------------------------------------------------------------------
// K4: main fused pass. grid = 16 categories x BCAT blocks; 256 thr = 4 waves.
// Per wave: 4 rows at a time; lane owns output cols {2l, 2l+1} of the 128-wide
// category slice. W tile (64KB) in LDS; rows staged transposed for b128
// broadcast reads. Epilogue: BN+leaky -> W2 -> butterfly -> logsoftmax -> out.
// ---------------------------------------------------------------------------
__global__ __launch_bounds__(256) void k_main(
    const float* __restrict__ F, const float* __restrict__ W1,
    const float* __restrict__ W2, const float* __restrict__ bias,
    const float* __restrict__ scale, const float* __restrict__ shiftv,
    const int* __restrict__ counts, const int* __restrict__ rowidx,
    float* __restrict__ out)
{
  __shared__ float Wl[128][128];   // 64 KB
  __shared__ float fT[4][128][4];  // 8 KB, per-wave transposed row staging
  const int tid = threadIdx.x;
  const int cat = (int)blockIdx.x >> 5;
  const int blk = (int)blockIdx.x & (BCAT - 1);
  int off = 0, cnt = 0;
  #pragma unroll
  for (int t = 0; t < NCAT; ++t) {
    int cv = counts[t];
    if (t < cat) off += cv;
    if (t == cat) cnt = cv;
  }
  for (int i = tid * 4; i < 16384; i += 1024) {
    int k = i >> 7, j = i & 127;
    *(float4*)&Wl[k][j] = *(const float4*)&W1[(size_t)k * 2048 + cat * 128 + j];
  }
  const int wid = tid >> 6, lane = tid & 63;
  const int d0 = lane * 2;
  float w2a[6], w2b[6], bi[6];
  const float* w2p = W2 + cat * 768 + d0 * 6;
  #pragma unroll
  for (int s = 0; s < 6; ++s) { w2a[s] = w2p[s]; w2b[s] = w2p[6 + s]; bi[s] = bias[s]; }
  const float sc0 = scale[cat * 128 + d0], sc1 = scale[cat * 128 + d0 + 1];
  const float sh0 = shiftv[cat * 128 + d0], sh1 = shiftv[cat * 128 + d0 + 1];
  const int shc = c_shift[cat], lnc = c_len[cat];
  __syncthreads();
  const int chunk = (cnt + BCAT - 1) / BCAT;
  const int start = off + blk * chunk;
  const int end = min(start + chunk, off + cnt);
  for (int q = start + wid * 4; q < end; q += 16) {
    const int nr = min(4, end - q);
    int rows[4];
    #pragma unroll
    for (int rr = 0; rr < 4; ++rr) rows[rr] = rowidx[min(q + rr, end - 1)];
    float4 g0, g1;
    g0.x = F[(size_t)rows[0] * 128 + lane];
    g0.y = F[(size_t)rows[1] * 128 + lane];
    g0.z = F[(size_t)rows[2] * 128 + lane];
    g0.w = F[(size_t)rows[3] * 128 + lane];
    g1.x = F[(size_t)rows[0] * 128 + 64 + lane];
    g1.y = F[(size_t)rows[1] * 128 + 64 + lane];
    g1.z = F[(size_t)rows[2] * 128 + 64 + lane];
    g1.w = F[(size_t)rows[3] * 128 + 64 + lane];
    *(float4*)&fT[wid][lane][0]      = g0;
    *(float4*)&fT[wid][lane + 64][0] = g1;
    float ax0 = 0.f, ay0 = 0.f, ax1 = 0.f, ay1 = 0.f;
    float ax2 = 0.f, ay2 = 0.f, ax3 = 0.f, ay3 = 0.f;
    #pragma unroll 4
    for (int k = 0; k < 128; ++k) {
      float4 f4 = *(const float4*)&fT[wid][k][0];   // broadcast
      float2 w  = *(const float2*)&Wl[k][d0];
      ax0 = fmaf(f4.x, w.x, ax0); ay0 = fmaf(f4.x, w.y, ay0);
      ax1 = fmaf(f4.y, w.x, ax1); ay1 = fmaf(f4.y, w.y, ay1);
      ax2 = fmaf(f4.z, w.x, ax2); ay2 = fmaf(f4.z, w.y, ay2);
      ax3 = fmaf(f4.w, w.x, ax3); ay3 = fmaf(f4.w, w.y, ay3);
    }
    const float vx[4] = {ax0, ax1, ax2, ax3};
    const float vy[4] = {ay0, ay1, ay2, ay3};
    #pragma unroll
    for (int rr = 0; rr < 4; ++rr) {
      if (rr >= nr) break;   // nr is wave-uniform: shfl below is safe
      float a0 = vx[rr] * sc0 + sh0; a0 = (a0 >= 0.f) ? a0 : 0.2f * a0;
      float a1 = vy[rr] * sc1 + sh1; a1 = (a1 >= 0.f) ? a1 : 0.2f * a1;
      float p[6];
      #pragma unroll
      for (int s = 0; s < 6; ++s) p[s] = fmaf(a0, w2a[s], a1 * w2b[s]);
      #pragma unroll
      for (int dm = 1; dm < 64; dm <<= 1) {
        #pragma unroll
        for (int s = 0; s < 6; ++s) p[s] += __shfl_xor(p[s], dm);
      }
      #pragma unroll
      for (int s = 0; s < 6; ++s) p[s] += bi[s];
      float mx = fmaxf(fmaxf(fmaxf(p[0], p[1]), fmaxf(p[2], p[3])), fmaxf(p[4], p[5]));
      float e = __expf(p[0] - mx) + __expf(p[1] - mx) + __expf(p[2] - mx)
              + __expf(p[3] - mx) + __expf(p[4] - mx) + __expf(p[5] - mx);
      float lse = mx + __logf(e);
      if (lane < 54) {
        int si = lane - shc;
        float val = 0.f;
        if (si >= 0 && si < lnc) {
          float lv = si == 0 ? p[0] : si == 1 ? p[1] : si == 2 ? p[2]
                   : si == 3 ? p[3] : si == 4 ? p[4] : p[5];
          val = lv - lse;
        }
        out[(size_t)rows[rr] * 54 + lane] = val;
      }
    }
  }
}

// ---------------------------------------------------------------------------
// Host launcher
// ---------------------------------------------------------------------------
extern "C" void kernel_launch(void* const* d_in, const int* in_sizes, int n_in,
                              void* d_out, int out_size, void* d_ws, size_t ws_size,
                              hipStream_t stream) {
  const float* F     = (const float*)d_in[0];
  const float* W1    = (const float*)d_in[1];
  const float* gamma = (const float*)d_in[2];
  const float* beta  = (const float*)d_in[3];
  const float* W2    = (const float*)d_in[4];
  const float* bias  = (const float*)d_in[5];
  const int*   lab   = (const int*)d_in[6];
  float* out = (float*)d_out;

  char* ws = (char*)d_ws;
  float* G       = (float*)ws;               // 16384 f32 @ 0
  float* sv      = (float*)(ws + 65536);     // 128 f32
  int*   counts  = (int*)(ws + 66048);       // 16 i32
  int*   cursors = (int*)(ws + 66112);       // 16 i32
  float* scale   = (float*)(ws + 66176);     // 2048 f32
  float* shiftv  = (float*)(ws + 74368);     // 2048 f32
  int*   rowidx  = (int*)(ws + 82560);       // 65536 i32  (total 344704 B)

  hipMemsetAsync(d_ws, 0, 66176, stream);    // G, sv, counts, cursors
  hipLaunchKernelGGL(k_stats, dim3(256), dim3(256), 0, stream, F, lab, G, sv, counts);
  hipLaunchKernelGGL(k_params, dim3(128), dim3(256), 0, stream, G, sv, W1, gamma, beta, scale, shiftv);
  hipLaunchKernelGGL(k_scatter, dim3(256), dim3(256), 0, stream, lab, counts, cursors, rowidx);
  hipLaunchKernelGGL(k_main, dim3(NCAT * BCAT), dim3(256), 0, stream, F, W1, W2, bias,
                     scale, shiftv, counts, rowidx, out);
}

// Round 2
// 347.618 us; speedup vs baseline: 1.4134x; 1.4134x over previous
//
#include <hip/hip_runtime.h>

#define NROWS 65536
#define NCAT 16
#define BCAT 32   // blocks per category in k_main

__constant__ int c_shift[NCAT] = {0,4,6,8,12,16,19,22,24,28,34,36,42,45,48,51};
__constant__ int c_len[NCAT]   = {4,2,2,4,4,3,3,2,4,6,2,6,3,3,3,3};

// ws layout (bytes):
//   sv      @ 0       (128 f32)
//   counts  @ 512     (16 i32)
//   cursors @ 576     (16 i32)
//   scale   @ 640     (2048 f32)
//   shiftv  @ 8832    (2048 f32)
//   G       @ 17024   (16384 f32)
//   rowidx  @ 82560   (65536 i32)   -> ends 344704
//   Gpart   @ 344704  (256 * 16384 f32 = 16 MB)   [fast path only]

// ---------------------------------------------------------------------------
// K1a: per-block partial Gram (non-atomic stores), column sums, label histo.
// 256 blocks x 256 threads; block handles 256 rows; thread owns an 8x8 G tile.
// ---------------------------------------------------------------------------
__global__ __launch_bounds__(256) void k_stats_part(
    const float* __restrict__ F, const int* __restrict__ lab,
    float* __restrict__ Gpart, float* __restrict__ sv, int* __restrict__ counts)
{
  __shared__ float ft[16][132];
  __shared__ int hl[NCAT];
  const int tid = threadIdx.x;
  if (tid < NCAT) hl[tid] = 0;
  __syncthreads();
  const int rowbase = blockIdx.x * 256;
  atomicAdd(&hl[lab[rowbase + tid]], 1);

  float acc[8][8];
  #pragma unroll
  for (int a = 0; a < 8; ++a)
    #pragma unroll
    for (int b = 0; b < 8; ++b) acc[a][b] = 0.f;
  float cs = 0.f;
  const int ty = tid >> 4, tx = tid & 15;
  const int r = tid >> 4;
  const int c0 = (tid & 15) * 8;

  for (int t = 0; t < 16; ++t) {
    __syncthreads();
    const float* src = F + ((size_t)(rowbase + t * 16 + r)) * 128 + c0;
    float4 a0 = *(const float4*)src;
    float4 a1 = *(const float4*)(src + 4);
    *(float4*)&ft[r][c0]     = a0;
    *(float4*)&ft[r][c0 + 4] = a1;
    __syncthreads();
    #pragma unroll 2
    for (int rr = 0; rr < 16; ++rr) {
      float fa[8], fb[8];
      *(float4*)&fa[0] = *(const float4*)&ft[rr][ty * 8];
      *(float4*)&fa[4] = *(const float4*)&ft[rr][ty * 8 + 4];
      *(float4*)&fb[0] = *(const float4*)&ft[rr][tx * 8];
      *(float4*)&fb[4] = *(const float4*)&ft[rr][tx * 8 + 4];
      #pragma unroll
      for (int a = 0; a < 8; ++a)
        #pragma unroll
        for (int b = 0; b < 8; ++b)
          acc[a][b] = fmaf(fa[a], fb[b], acc[a][b]);
    }
    if (tid < 128) {
      #pragma unroll
      for (int rr = 0; rr < 16; ++rr) cs += ft[rr][tid];
    }
  }
  if (tid < 128) atomicAdd(&sv[tid], cs);
  if (tid < NCAT) atomicAdd(&counts[tid], hl[tid]);
  float* gp = Gpart + (size_t)blockIdx.x * 16384;
  #pragma unroll
  for (int a = 0; a < 8; ++a) {
    #pragma unroll
    for (int b = 0; b < 8; b += 4) {
      float4 v = make_float4(acc[a][b], acc[a][b + 1], acc[a][b + 2], acc[a][b + 3]);
      *(float4*)&gp[(ty * 8 + a) * 128 + tx * 8 + b] = v;
    }
  }
}

// K1b: reduce 256 partials -> G. 256 blocks x 64 threads, 1 element/thread.
__global__ __launch_bounds__(64) void k_reduce(
    const float* __restrict__ Gpart, float* __restrict__ G)
{
  const int e = blockIdx.x * 64 + threadIdx.x;
  float s = 0.f;
  #pragma unroll 8
  for (int p = 0; p < 256; ++p) s += Gpart[(size_t)p * 16384 + e];
  G[e] = s;
}

// K1-fallback: atomic version (used only if ws too small for partials).
__global__ __launch_bounds__(256) void k_stats_atomic(
    const float* __restrict__ F, const int* __restrict__ lab,
    float* __restrict__ G, float* __restrict__ sv, int* __restrict__ counts)
{
  __shared__ float ft[16][132];
  __shared__ int hl[NCAT];
  const int tid = threadIdx.x;
  if (tid < NCAT) hl[tid] = 0;
  __syncthreads();
  const int rowbase = blockIdx.x * 256;
  atomicAdd(&hl[lab[rowbase + tid]], 1);
  float acc[8][8];
  #pragma unroll
  for (int a = 0; a < 8; ++a)
    #pragma unroll
    for (int b = 0; b < 8; ++b) acc[a][b] = 0.f;
  float cs = 0.f;
  const int ty = tid >> 4, tx = tid & 15;
  const int r = tid >> 4;
  const int c0 = (tid & 15) * 8;
  for (int t = 0; t < 16; ++t) {
    __syncthreads();
    const float* src = F + ((size_t)(rowbase + t * 16 + r)) * 128 + c0;
    float4 a0 = *(const float4*)src;
    float4 a1 = *(const float4*)(src + 4);
    *(float4*)&ft[r][c0]     = a0;
    *(float4*)&ft[r][c0 + 4] = a1;
    __syncthreads();
    #pragma unroll 2
    for (int rr = 0; rr < 16; ++rr) {
      float fa[8], fb[8];
      *(float4*)&fa[0] = *(const float4*)&ft[rr][ty * 8];
      *(float4*)&fa[4] = *(const float4*)&ft[rr][ty * 8 + 4];
      *(float4*)&fb[0] = *(const float4*)&ft[rr][tx * 8];
      *(float4*)&fb[4] = *(const float4*)&ft[rr][tx * 8 + 4];
      #pragma unroll
      for (int a = 0; a < 8; ++a)
        #pragma unroll
        for (int b = 0; b < 8; ++b)
          acc[a][b] = fmaf(fa[a], fb[b], acc[a][b]);
    }
    if (tid < 128) {
      #pragma unroll
      for (int rr = 0; rr < 16; ++rr) cs += ft[rr][tid];
    }
  }
  if (tid < 128) atomicAdd(&sv[tid], cs);
  if (tid < NCAT) atomicAdd(&counts[tid], hl[tid]);
  #pragma unroll
  for (int a = 0; a < 8; ++a)
    #pragma unroll
    for (int b = 0; b < 8; ++b)
      atomicAdd(&G[(ty * 8 + a) * 128 + tx * 8 + b], acc[a][b]);
}

// ---------------------------------------------------------------------------
// K2: BN parameters. var_j = w_j^T G w_j / N - mean_j^2 ; scale/shift.
// ---------------------------------------------------------------------------
__global__ __launch_bounds__(256) void k_params(
    const float* __restrict__ G, const float* __restrict__ sv,
    const float* __restrict__ W1, const float* __restrict__ gamma,
    const float* __restrict__ beta, float* __restrict__ scale,
    float* __restrict__ shiftv)
{
  __shared__ float Gl[128][133];
  __shared__ float Wl[128][16];
  __shared__ float redq[16][16];
  __shared__ float redm[16][16];
  const int tid = threadIdx.x;
  const int jb = blockIdx.x * 16;
  for (int i = tid; i < 16384; i += 256) Gl[i >> 7][i & 127] = G[i];
  for (int i = tid; i < 2048; i += 256) {
    int k = i >> 4, col = i & 15;
    Wl[k][col] = W1[(size_t)k * 2048 + jb + col];
  }
  __syncthreads();
  const int col = tid & 15, part = tid >> 4;
  float msq = 0.f, mean = 0.f;
  for (int ii = 0; ii < 8; ++ii) {
    const int i = part * 8 + ii;
    const float wi = Wl[i][col];
    float inner = 0.f;
    #pragma unroll 8
    for (int k = 0; k < 128; ++k) inner = fmaf(Gl[i][k], Wl[k][col], inner);
    msq = fmaf(wi, inner, msq);
  }
  #pragma unroll
  for (int kk = 0; kk < 8; ++kk) {
    const int k = part * 8 + kk;
    mean = fmaf(sv[k], Wl[k][col], mean);
  }
  redq[part][col] = msq;
  redm[part][col] = mean;
  __syncthreads();
  if (tid < 16) {
    float q = 0.f, m = 0.f;
    #pragma unroll
    for (int p = 0; p < 16; ++p) { q += redq[p][tid]; m += redm[p][tid]; }
    m *= (1.f / 65536.f);
    q *= (1.f / 65536.f);
    float var = q - m * m;
    float sc = gamma[jb + tid] * rsqrtf(var + 1e-5f);
    scale[jb + tid] = sc;
    shiftv[jb + tid] = beta[jb + tid] - m * sc;
  }
}

// ---------------------------------------------------------------------------
// K3: compact row indices by category (wave-aggregated atomics).
// ---------------------------------------------------------------------------
__global__ __launch_bounds__(256) void k_scatter(
    const int* __restrict__ lab, const int* __restrict__ counts,
    int* __restrict__ cursors, int* __restrict__ rowidx)
{
  const int n = blockIdx.x * 256 + threadIdx.x;
  const int c = lab[n];
  int off = 0;
  #pragma unroll
  for (int t = 0; t < NCAT; ++t) off += (t < c) ? counts[t] : 0;
  const int lane = threadIdx.x & 63;
  const unsigned long long lanebit = 1ull << lane;
  for (int cc = 0; cc < NCAT; ++cc) {
    unsigned long long m = __ballot(c == cc);
    if (c == cc) {
      int rank = (int)__popcll(m & (lanebit - 1));
      int leader = __ffsll((unsigned long long)m) - 1;
      int base = 0;
      if (lane == leader) base = atomicAdd(&cursors[cc], (int)__popcll(m));
      base = __shfl(base, leader);
      rowidx[off + base + rank] = n;
    }
  }
}

// ---------------------------------------------------------------------------
// K4: main fused pass. grid = 16 cat x BCAT blocks; 256 thr = 4 waves.
// 8 rows/wave per iteration; lane owns output cols (lane, lane+64) of the
// 128-wide category slice -> W reads are two conflict-free b32s; fT broadcast
// b128s serve 16 FMAs. LDS 80KB -> 2 blocks/CU.
// ---------------------------------------------------------------------------
__global__ __launch_bounds__(256) void k_main(
    const float* __restrict__ F, const float* __restrict__ W1,
    const float* __restrict__ W2, const float* __restrict__ bias,
    const float* __restrict__ scale, const float* __restrict__ shiftv,
    const int* __restrict__ counts, const int* __restrict__ rowidx,
    float* __restrict__ out)
{
  __shared__ float Wl[128][128];   // 64 KB
  __shared__ float fT[4][128][8];  // 16 KB, per-wave k-major row staging
  const int tid = threadIdx.x;
  const int cat = (int)blockIdx.x >> 5;
  const int blk = (int)blockIdx.x & (BCAT - 1);
  int off = 0, cnt = 0;
  #pragma unroll
  for (int t = 0; t < NCAT; ++t) {
    int cv = counts[t];
    if (t < cat) off += cv;
    if (t == cat) cnt = cv;
  }
  for (int i = tid * 4; i < 16384; i += 1024) {
    int k = i >> 7, j = i & 127;
    *(float4*)&Wl[k][j] = *(const float4*)&W1[(size_t)k * 2048 + cat * 128 + j];
  }
  const int wid = tid >> 6, lane = tid & 63;
  float w2a[6], w2b[6], bi[6];
  const float* w2p = W2 + cat * 768 + lane * 6;
  #pragma unroll
  for (int s = 0; s < 6; ++s) { w2a[s] = w2p[s]; w2b[s] = w2p[64 * 6 + s]; bi[s] = bias[s]; }
  const float sc0 = scale[cat * 128 + lane], sc1 = scale[cat * 128 + 64 + lane];
  const float sh0 = shiftv[cat * 128 + lane], sh1 = shiftv[cat * 128 + 64 + lane];
  const int shc = c_shift[cat], lnc = c_len[cat];
  __syncthreads();
  const int chunk = (cnt + BCAT - 1) / BCAT;
  const int start = off + blk * chunk;
  const int end = min(start + chunk, off + cnt);
  for (int q = start + wid * 8; q < end; q += 32) {
    const int nr = min(8, end - q);           // wave-uniform
    int rows[8];
    #pragma unroll
    for (int rr = 0; rr < 8; ++rr) rows[rr] = rowidx[min(q + rr, end - 1)];
    #pragma unroll
    for (int rr = 0; rr < 8; ++rr) {
      fT[wid][lane][rr]      = F[(size_t)rows[rr] * 128 + lane];
      fT[wid][lane + 64][rr] = F[(size_t)rows[rr] * 128 + 64 + lane];
    }
    float acc0[8], acc1[8];
    #pragma unroll
    for (int rr = 0; rr < 8; ++rr) { acc0[rr] = 0.f; acc1[rr] = 0.f; }
    #pragma unroll 4
    for (int k = 0; k < 128; ++k) {
      float4 fa = *(const float4*)&fT[wid][k][0];   // rows 0..3 (broadcast)
      float4 fb = *(const float4*)&fT[wid][k][4];   // rows 4..7 (broadcast)
      float w0 = Wl[k][lane];
      float w1 = Wl[k][lane + 64];
      acc0[0] = fmaf(fa.x, w0, acc0[0]); acc1[0] = fmaf(fa.x, w1, acc1[0]);
      acc0[1] = fmaf(fa.y, w0, acc0[1]); acc1[1] = fmaf(fa.y, w1, acc1[1]);
      acc0[2] = fmaf(fa.z, w0, acc0[2]); acc1[2] = fmaf(fa.z, w1, acc1[2]);
      acc0[3] = fmaf(fa.w, w0, acc0[3]); acc1[3] = fmaf(fa.w, w1, acc1[3]);
      acc0[4] = fmaf(fb.x, w0, acc0[4]); acc1[4] = fmaf(fb.x, w1, acc1[4]);
      acc0[5] = fmaf(fb.y, w0, acc0[5]); acc1[5] = fmaf(fb.y, w1, acc1[5]);
      acc0[6] = fmaf(fb.z, w0, acc0[6]); acc1[6] = fmaf(fb.z, w1, acc1[6]);
      acc0[7] = fmaf(fb.w, w0, acc0[7]); acc1[7] = fmaf(fb.w, w1, acc1[7]);
    }
    #pragma unroll
    for (int rr = 0; rr < 8; ++rr) {
      if (rr >= nr) break;                    // nr wave-uniform: shfl safe
      float a0 = acc0[rr] * sc0 + sh0; a0 = (a0 >= 0.f) ? a0 : 0.2f * a0;
      float a1 = acc1[rr] * sc1 + sh1; a1 = (a1 >= 0.f) ? a1 : 0.2f * a1;
      float p[6];
      #pragma unroll
      for (int s = 0; s < 6; ++s) p[s] = fmaf(a0, w2a[s], a1 * w2b[s]);
      #pragma unroll
      for (int dm = 1; dm < 64; dm <<= 1) {
        #pragma unroll
        for (int s = 0; s < 6; ++s) p[s] += __shfl_xor(p[s], dm);
      }
      #pragma unroll
      for (int s = 0; s < 6; ++s) p[s] += bi[s];
      float mx = fmaxf(fmaxf(fmaxf(p[0], p[1]), fmaxf(p[2], p[3])), fmaxf(p[4], p[5]));
      float e = __expf(p[0] - mx) + __expf(p[1] - mx) + __expf(p[2] - mx)
              + __expf(p[3] - mx) + __expf(p[4] - mx) + __expf(p[5] - mx);
      float lse = mx + __logf(e);
      if (lane < 54) {
        int si = lane - shc;
        float val = 0.f;
        if (si >= 0 && si < lnc) {
          float lv = si == 0 ? p[0] : si == 1 ? p[1] : si == 2 ? p[2]
                   : si == 3 ? p[3] : si == 4 ? p[4] : p[5];
          val = lv - lse;
        }
        out[(size_t)rows[rr] * 54 + lane] = val;
      }
    }
  }
}

// ---------------------------------------------------------------------------
// Host launcher
// ---------------------------------------------------------------------------
extern "C" void kernel_launch(void* const* d_in, const int* in_sizes, int n_in,
                              void* d_out, int out_size, void* d_ws, size_t ws_size,
                              hipStream_t stream) {
  const float* F     = (const float*)d_in[0];
  const float* W1    = (const float*)d_in[1];
  const float* gamma = (const float*)d_in[2];
  const float* beta  = (const float*)d_in[3];
  const float* W2    = (const float*)d_in[4];
  const float* bias  = (const float*)d_in[5];
  const int*   lab   = (const int*)d_in[6];
  float* out = (float*)d_out;

  char* ws = (char*)d_ws;
  float* sv      = (float*)(ws + 0);
  int*   counts  = (int*)(ws + 512);
  int*   cursors = (int*)(ws + 576);
  float* scale   = (float*)(ws + 640);
  float* shiftv  = (float*)(ws + 8832);
  float* G       = (float*)(ws + 17024);
  int*   rowidx  = (int*)(ws + 82560);
  float* Gpart   = (float*)(ws + 344704);

  const size_t need = 344704 + (size_t)256 * 16384 * 4;  // ~16.3 MB
  if (ws_size >= need) {
    hipMemsetAsync(d_ws, 0, 640, stream);   // sv, counts, cursors
    hipLaunchKernelGGL(k_stats_part, dim3(256), dim3(256), 0, stream, F, lab, Gpart, sv, counts);
    hipLaunchKernelGGL(k_reduce, dim3(256), dim3(64), 0, stream, Gpart, G);
  } else {
    hipMemsetAsync(d_ws, 0, 82560, stream); // + G zeroed for atomics
    hipLaunchKernelGGL(k_stats_atomic, dim3(256), dim3(256), 0, stream, F, lab, G, sv, counts);
  }
  hipLaunchKernelGGL(k_params, dim3(128), dim3(256), 0, stream, G, sv, W1, gamma, beta, scale, shiftv);
  hipLaunchKernelGGL(k_scatter, dim3(256), dim3(256), 0, stream, lab, counts, cursors, rowidx);
  hipLaunchKernelGGL(k_main, dim3(NCAT * BCAT), dim3(256), 0, stream, F, W1, W2, bias,
                     scale, shiftv, counts, rowidx, out);
}

// Round 3
// 153.300 us; speedup vs baseline: 3.2050x; 2.2676x over previous
//
#include <hip/hip_runtime.h>

#define NROWS 65536
#define NCAT 16
#define BCAT 32   // blocks per category in k_main

__constant__ int c_shift[NCAT] = {0,4,6,8,12,16,19,22,24,28,34,36,42,45,48,51};
__constant__ int c_len[NCAT]   = {4,2,2,4,4,3,3,2,4,6,2,6,3,3,3,3};

// ws layout (bytes):
//   sv      @ 0       (128 f32)
//   counts  @ 512     (16 i32)
//   blkcnt  @ 576     (256*16 i32)  -> 16960
//   offs    @ 16960   (256*16 i32)  -> 33344
//   scale   @ 33344   (2048 f32)    -> 41536
//   shiftv  @ 41536   (2048 f32)    -> 49728
//   G       @ 49728   (16384 f32)   -> 115264
//   rowidx  @ 115264  (65536 i32)   -> 377408
//   Gpart   @ 377408  (256*16384 f32 = 16 MB)  [fast path only]

// ---------------------------------------------------------------------------
// K1: per-block partial Gram + column sums + per-block label histogram.
// 256 blocks x 1024 threads; block = 256 rows; thread owns a 4x4 G tile.
// PART=true: non-atomic per-block partial store; else atomicAdd fallback.
// ---------------------------------------------------------------------------
template<bool PART>
__global__ __launch_bounds__(1024) void k_stats_t(
    const float* __restrict__ F, const int* __restrict__ lab,
    float* __restrict__ Gdst, float* __restrict__ sv, int* __restrict__ blkcnt)
{
  __shared__ float ft[32][132];   // 32-row stage, pad to spread banks
  __shared__ int hl[NCAT];
  const int tid = threadIdx.x;
  if (tid < NCAT) hl[tid] = 0;
  __syncthreads();
  const int rowbase = blockIdx.x * 256;
  if (tid < 256) atomicAdd(&hl[lab[rowbase + tid]], 1);

  float acc[4][4] = {};
  float cs = 0.f;
  const int ty = tid >> 5, tx = tid & 31;   // 32x32 thread tile grid
  const int sr = tid >> 5;                  // staging row 0..31
  const int sc = (tid & 31) * 4;            // staging col

  for (int t = 0; t < 8; ++t) {
    __syncthreads();
    *(float4*)&ft[sr][sc] =
        *(const float4*)(F + ((size_t)(rowbase + t * 32 + sr)) * 128 + sc);
    __syncthreads();
    #pragma unroll 4
    for (int rr = 0; rr < 32; ++rr) {
      float4 fa = *(const float4*)&ft[rr][ty * 4];
      float4 fb = *(const float4*)&ft[rr][tx * 4];
      const float av[4] = {fa.x, fa.y, fa.z, fa.w};
      const float bv[4] = {fb.x, fb.y, fb.z, fb.w};
      #pragma unroll
      for (int a = 0; a < 4; ++a)
        #pragma unroll
        for (int b = 0; b < 4; ++b)
          acc[a][b] = fmaf(av[a], bv[b], acc[a][b]);
    }
    if (tid < 128) {
      #pragma unroll
      for (int rr = 0; rr < 32; ++rr) cs += ft[rr][tid];
    }
  }
  if (tid < 128) atomicAdd(&sv[tid], cs);
  if (tid < NCAT) blkcnt[blockIdx.x * NCAT + tid] = hl[tid];
  if (PART) {
    float* gp = Gdst + (size_t)blockIdx.x * 16384;
    #pragma unroll
    for (int a = 0; a < 4; ++a) {
      float4 v = make_float4(acc[a][0], acc[a][1], acc[a][2], acc[a][3]);
      *(float4*)&gp[(ty * 4 + a) * 128 + tx * 4] = v;
    }
  } else {
    #pragma unroll
    for (int a = 0; a < 4; ++a)
      #pragma unroll
      for (int b = 0; b < 4; ++b)
        atomicAdd(&Gdst[(ty * 4 + a) * 128 + tx * 4 + b], acc[a][b]);
  }
}

// K1b: reduce 256 partials -> G. 256 blocks x 64 threads, 1 element/thread.
__global__ __launch_bounds__(64) void k_reduce(
    const float* __restrict__ Gpart, float* __restrict__ G)
{
  const int e = blockIdx.x * 64 + threadIdx.x;
  float s = 0.f;
  #pragma unroll 8
  for (int p = 0; p < 256; ++p) s += Gpart[(size_t)p * 16384 + e];
  G[e] = s;
}

// ---------------------------------------------------------------------------
// K1c: prefix sums over blkcnt -> offs[block][cat], counts[cat]. 1 block.
// tid = part*16 + cat; part covers blocks part*16..part*16+15.
// ---------------------------------------------------------------------------
__global__ __launch_bounds__(256) void k_prefix(
    const int* __restrict__ blkcnt, int* __restrict__ offs,
    int* __restrict__ counts)
{
  __shared__ int ps[16][16];    // chunk totals [part][cat]
  __shared__ int ps2[16][16];   // exclusive chunk prefix
  __shared__ int tot[16];
  __shared__ int catbase[16];
  const int tid = threadIdx.x;
  const int part = tid >> 4, cat = tid & 15;
  int v[16];
  int s = 0;
  #pragma unroll
  for (int i = 0; i < 16; ++i) {
    v[i] = s;
    s += blkcnt[(part * 16 + i) * 16 + cat];
  }
  ps[part][cat] = s;
  __syncthreads();
  if (part == 0) {
    int acc = 0;
    #pragma unroll
    for (int p = 0; p < 16; ++p) { ps2[p][cat] = acc; acc += ps[p][cat]; }
    tot[cat] = acc;
    counts[cat] = acc;
  }
  __syncthreads();
  if (tid == 0) {
    int acc = 0;
    #pragma unroll
    for (int c = 0; c < 16; ++c) { catbase[c] = acc; acc += tot[c]; }
  }
  __syncthreads();
  const int base = catbase[cat] + ps2[part][cat];
  #pragma unroll
  for (int i = 0; i < 16; ++i)
    offs[(part * 16 + i) * 16 + cat] = base + v[i];
}

// ---------------------------------------------------------------------------
// K3: compact row indices by category — atomic-free, deterministic.
// rank = (earlier waves' same-cat counts) + (earlier lanes in my wave).
// ---------------------------------------------------------------------------
__global__ __launch_bounds__(256) void k_scatter(
    const int* __restrict__ lab, const int* __restrict__ offs,
    int* __restrict__ rowidx)
{
  __shared__ int wc[4][NCAT];
  const int tid = threadIdx.x;
  const int wid = tid >> 6, lane = tid & 63;
  const int n = blockIdx.x * 256 + tid;
  const int c = lab[n];
  const unsigned long long lanebit = 1ull << lane;
  int myrank = 0;
  #pragma unroll
  for (int cc = 0; cc < NCAT; ++cc) {
    unsigned long long m = __ballot(c == cc);
    if (lane == 0) wc[wid][cc] = (int)__popcll(m);
    if (c == cc) myrank = (int)__popcll(m & (lanebit - 1));
  }
  __syncthreads();
  int base = 0;
  #pragma unroll
  for (int w = 0; w < 4; ++w)
    if (w < wid) base += wc[w][c];
  rowidx[offs[blockIdx.x * NCAT + c] + base + myrank] = n;
}

// ---------------------------------------------------------------------------
// K2: BN parameters. var_j = w_j^T G w_j / N - mean_j^2 ; scale/shift.
// ---------------------------------------------------------------------------
__global__ __launch_bounds__(256) void k_params(
    const float* __restrict__ G, const float* __restrict__ sv,
    const float* __restrict__ W1, const float* __restrict__ gamma,
    const float* __restrict__ beta, float* __restrict__ scale,
    float* __restrict__ shiftv)
{
  __shared__ float Gl[128][133];
  __shared__ float Wl[128][16];
  __shared__ float redq[16][16];
  __shared__ float redm[16][16];
  const int tid = threadIdx.x;
  const int jb = blockIdx.x * 16;
  for (int i = tid; i < 16384; i += 256) Gl[i >> 7][i & 127] = G[i];
  for (int i = tid; i < 2048; i += 256) {
    int k = i >> 4, col = i & 15;
    Wl[k][col] = W1[(size_t)k * 2048 + jb + col];
  }
  __syncthreads();
  const int col = tid & 15, part = tid >> 4;
  float msq = 0.f, mean = 0.f;
  for (int ii = 0; ii < 8; ++ii) {
    const int i = part * 8 + ii;
    const float wi = Wl[i][col];
    float inner = 0.f;
    #pragma unroll 8
    for (int k = 0; k < 128; ++k) inner = fmaf(Gl[i][k], Wl[k][col], inner);
    msq = fmaf(wi, inner, msq);
  }
  #pragma unroll
  for (int kk = 0; kk < 8; ++kk) {
    const int k = part * 8 + kk;
    mean = fmaf(sv[k], Wl[k][col], mean);
  }
  redq[part][col] = msq;
  redm[part][col] = mean;
  __syncthreads();
  if (tid < 16) {
    float q = 0.f, m = 0.f;
    #pragma unroll
    for (int p = 0; p < 16; ++p) { q += redq[p][tid]; m += redm[p][tid]; }
    m *= (1.f / 65536.f);
    q *= (1.f / 65536.f);
    float var = q - m * m;
    float sc = gamma[jb + tid] * rsqrtf(var + 1e-5f);
    scale[jb + tid] = sc;
    shiftv[jb + tid] = beta[jb + tid] - m * sc;
  }
}

// ---------------------------------------------------------------------------
// K4: main fused pass. grid = 16 cat x BCAT blocks; 256 thr = 4 waves.
// 8 rows/wave per iteration; lane owns output cols (lane, lane+64).
// ---------------------------------------------------------------------------
__global__ __launch_bounds__(256) void k_main(
    const float* __restrict__ F, const float* __restrict__ W1,
    const float* __restrict__ W2, const float* __restrict__ bias,
    const float* __restrict__ scale, const float* __restrict__ shiftv,
    const int* __restrict__ counts, const int* __restrict__ rowidx,
    float* __restrict__ out)
{
  __shared__ float Wl[128][128];   // 64 KB
  __shared__ float fT[4][128][8];  // 16 KB, per-wave k-major row staging
  const int tid = threadIdx.x;
  const int cat = (int)blockIdx.x >> 5;
  const int blk = (int)blockIdx.x & (BCAT - 1);
  int off = 0, cnt = 0;
  #pragma unroll
  for (int t = 0; t < NCAT; ++t) {
    int cv = counts[t];
    if (t < cat) off += cv;
    if (t == cat) cnt = cv;
  }
  for (int i = tid * 4; i < 16384; i += 1024) {
    int k = i >> 7, j = i & 127;
    *(float4*)&Wl[k][j] = *(const float4*)&W1[(size_t)k * 2048 + cat * 128 + j];
  }
  const int wid = tid >> 6, lane = tid & 63;
  float w2a[6], w2b[6], bi[6];
  const float* w2p = W2 + cat * 768 + lane * 6;
  #pragma unroll
  for (int s = 0; s < 6; ++s) { w2a[s] = w2p[s]; w2b[s] = w2p[64 * 6 + s]; bi[s] = bias[s]; }
  const float sc0 = scale[cat * 128 + lane], sc1 = scale[cat * 128 + 64 + lane];
  const float sh0 = shiftv[cat * 128 + lane], sh1 = shiftv[cat * 128 + 64 + lane];
  const int shc = c_shift[cat], lnc = c_len[cat];
  __syncthreads();
  const int chunk = (cnt + BCAT - 1) / BCAT;
  const int start = off + blk * chunk;
  const int end = min(start + chunk, off + cnt);
  for (int q = start + wid * 8; q < end; q += 32) {
    const int nr = min(8, end - q);           // wave-uniform
    int rows[8];
    #pragma unroll
    for (int rr = 0; rr < 8; ++rr) rows[rr] = rowidx[min(q + rr, end - 1)];
    #pragma unroll
    for (int rr = 0; rr < 8; ++rr) {
      fT[wid][lane][rr]      = F[(size_t)rows[rr] * 128 + lane];
      fT[wid][lane + 64][rr] = F[(size_t)rows[rr] * 128 + 64 + lane];
    }
    float acc0[8], acc1[8];
    #pragma unroll
    for (int rr = 0; rr < 8; ++rr) { acc0[rr] = 0.f; acc1[rr] = 0.f; }
    #pragma unroll 4
    for (int k = 0; k < 128; ++k) {
      float4 fa = *(const float4*)&fT[wid][k][0];
      float4 fb = *(const float4*)&fT[wid][k][4];
      float w0 = Wl[k][lane];
      float w1 = Wl[k][lane + 64];
      acc0[0] = fmaf(fa.x, w0, acc0[0]); acc1[0] = fmaf(fa.x, w1, acc1[0]);
      acc0[1] = fmaf(fa.y, w0, acc0[1]); acc1[1] = fmaf(fa.y, w1, acc1[1]);
      acc0[2] = fmaf(fa.z, w0, acc0[2]); acc1[2] = fmaf(fa.z, w1, acc1[2]);
      acc0[3] = fmaf(fa.w, w0, acc0[3]); acc1[3] = fmaf(fa.w, w1, acc1[3]);
      acc0[4] = fmaf(fb.x, w0, acc0[4]); acc1[4] = fmaf(fb.x, w1, acc1[4]);
      acc0[5] = fmaf(fb.y, w0, acc0[5]); acc1[5] = fmaf(fb.y, w1, acc1[5]);
      acc0[6] = fmaf(fb.z, w0, acc0[6]); acc1[6] = fmaf(fb.z, w1, acc1[6]);
      acc0[7] = fmaf(fb.w, w0, acc0[7]); acc1[7] = fmaf(fb.w, w1, acc1[7]);
    }
    #pragma unroll
    for (int rr = 0; rr < 8; ++rr) {
      if (rr >= nr) break;                    // nr wave-uniform: shfl safe
      float a0 = acc0[rr] * sc0 + sh0; a0 = (a0 >= 0.f) ? a0 : 0.2f * a0;
      float a1 = acc1[rr] * sc1 + sh1; a1 = (a1 >= 0.f) ? a1 : 0.2f * a1;
      float p[6];
      #pragma unroll
      for (int s = 0; s < 6; ++s) p[s] = fmaf(a0, w2a[s], a1 * w2b[s]);
      #pragma unroll
      for (int dm = 1; dm < 64; dm <<= 1) {
        #pragma unroll
        for (int s = 0; s < 6; ++s) p[s] += __shfl_xor(p[s], dm);
      }
      #pragma unroll
      for (int s = 0; s < 6; ++s) p[s] += bi[s];
      float mx = fmaxf(fmaxf(fmaxf(p[0], p[1]), fmaxf(p[2], p[3])), fmaxf(p[4], p[5]));
      float e = __expf(p[0] - mx) + __expf(p[1] - mx) + __expf(p[2] - mx)
              + __expf(p[3] - mx) + __expf(p[4] - mx) + __expf(p[5] - mx);
      float lse = mx + __logf(e);
      if (lane < 54) {
        int si = lane - shc;
        float val = 0.f;
        if (si >= 0 && si < lnc) {
          float lv = si == 0 ? p[0] : si == 1 ? p[1] : si == 2 ? p[2]
                   : si == 3 ? p[3] : si == 4 ? p[4] : p[5];
          val = lv - lse;
        }
        out[(size_t)rows[rr] * 54 + lane] = val;
      }
    }
  }
}

// ---------------------------------------------------------------------------
// Host launcher
// ---------------------------------------------------------------------------
extern "C" void kernel_launch(void* const* d_in, const int* in_sizes, int n_in,
                              void* d_out, int out_size, void* d_ws, size_t ws_size,
                              hipStream_t stream) {
  const float* F     = (const float*)d_in[0];
  const float* W1    = (const float*)d_in[1];
  const float* gamma = (const float*)d_in[2];
  const float* beta  = (const float*)d_in[3];
  const float* W2    = (const float*)d_in[4];
  const float* bias  = (const float*)d_in[5];
  const int*   lab   = (const int*)d_in[6];
  float* out = (float*)d_out;

  char* ws = (char*)d_ws;
  float* sv      = (float*)(ws + 0);
  int*   counts  = (int*)(ws + 512);
  int*   blkcnt  = (int*)(ws + 576);
  int*   offs    = (int*)(ws + 16960);
  float* scale   = (float*)(ws + 33344);
  float* shiftv  = (float*)(ws + 41536);
  float* G       = (float*)(ws + 49728);
  int*   rowidx  = (int*)(ws + 115264);
  float* Gpart   = (float*)(ws + 377408);

  const size_t need = 377408 + (size_t)256 * 16384 * 4;  // ~17.2 MB
  if (ws_size >= need) {
    hipMemsetAsync(d_ws, 0, 576, stream);    // sv (+counts, harmless)
    hipLaunchKernelGGL(k_stats_t<true>, dim3(256), dim3(1024), 0, stream,
                       F, lab, Gpart, sv, blkcnt);
    hipLaunchKernelGGL(k_reduce, dim3(256), dim3(64), 0, stream, Gpart, G);
  } else {
    hipMemsetAsync(d_ws, 0, 115264, stream); // also zero G for atomics
    hipLaunchKernelGGL(k_stats_t<false>, dim3(256), dim3(1024), 0, stream,
                       F, lab, G, sv, blkcnt);
  }
  hipLaunchKernelGGL(k_prefix, dim3(1), dim3(256), 0, stream, blkcnt, offs, counts);
  hipLaunchKernelGGL(k_scatter, dim3(256), dim3(256), 0, stream, lab, offs, rowidx);
  hipLaunchKernelGGL(k_params, dim3(128), dim3(256), 0, stream, G, sv, W1, gamma, beta, scale, shiftv);
  hipLaunchKernelGGL(k_main, dim3(NCAT * BCAT), dim3(256), 0, stream, F, W1, W2, bias,
                     scale, shiftv, counts, rowidx, out);
}

// Round 4
// 116.082 us; speedup vs baseline: 4.2326x; 1.3206x over previous
//
#include <hip/hip_runtime.h>

#define NROWS 65536
#define NCAT 16
#define BCAT 32   // blocks per category in k_main

typedef __attribute__((ext_vector_type(8))) short short8v;
typedef __attribute__((ext_vector_type(4))) float float4v;

__constant__ int c_shift[NCAT] = {0,4,6,8,12,16,19,22,24,28,34,36,42,45,48,51};
__constant__ int c_len[NCAT]   = {4,2,2,4,4,3,3,2,4,6,2,6,3,3,3,3};

// ws layout (bytes):
//   sv      @ 0       (128 f32)
//   counts  @ 512     (16 i32)
//   blkcnt  @ 576     (256*16 i32)  -> 16960
//   offs    @ 16960   (256*16 i32)  -> 33344
//   scale   @ 33344   (2048 f32)    -> 41536
//   shiftv  @ 41536   (2048 f32)    -> 49728
//   G       @ 49728   (16384 f32)   -> 115264
//   rowidx  @ 115264  (65536 i32)   -> 377408
//   Gpart   @ 377408  (256*16384 f32 = 16 MB)  [k_stats_part -> k_reduce]
//   Wlb     @ 377408  (16*32*64*8 bf16 = 512 KB) [k_wswz AFTER k_reduce: reuses
//                      the then-dead Gpart region; stream order guarantees safety]

static inline __device__ unsigned short f2bf(float x) {
  union { float f; unsigned int u; } v; v.f = x;
  unsigned int r = v.u + 0x7fffu + ((v.u >> 16) & 1u);   // RNE
  return (unsigned short)(r >> 16);
}

// ---------------------------------------------------------------------------
// K1: per-block partial Gram + column sums + per-block label histogram.
// 256 blocks x 1024 threads; block = 256 rows; thread owns a 4x4 G tile.
// ---------------------------------------------------------------------------
template<bool PART>
__global__ __launch_bounds__(1024) void k_stats_t(
    const float* __restrict__ F, const int* __restrict__ lab,
    float* __restrict__ Gdst, float* __restrict__ sv, int* __restrict__ blkcnt)
{
  __shared__ float ft[32][132];
  __shared__ int hl[NCAT];
  const int tid = threadIdx.x;
  if (tid < NCAT) hl[tid] = 0;
  __syncthreads();
  const int rowbase = blockIdx.x * 256;
  if (tid < 256) atomicAdd(&hl[lab[rowbase + tid]], 1);

  float acc[4][4] = {};
  float cs = 0.f;
  const int ty = tid >> 5, tx = tid & 31;
  const int sr = tid >> 5;
  const int sc = (tid & 31) * 4;

  for (int t = 0; t < 8; ++t) {
    __syncthreads();
    *(float4*)&ft[sr][sc] =
        *(const float4*)(F + ((size_t)(rowbase + t * 32 + sr)) * 128 + sc);
    __syncthreads();
    #pragma unroll 4
    for (int rr = 0; rr < 32; ++rr) {
      float4 fa = *(const float4*)&ft[rr][ty * 4];
      float4 fb = *(const float4*)&ft[rr][tx * 4];
      const float av[4] = {fa.x, fa.y, fa.z, fa.w};
      const float bv[4] = {fb.x, fb.y, fb.z, fb.w};
      #pragma unroll
      for (int a = 0; a < 4; ++a)
        #pragma unroll
        for (int b = 0; b < 4; ++b)
          acc[a][b] = fmaf(av[a], bv[b], acc[a][b]);
    }
    if (tid < 128) {
      #pragma unroll
      for (int rr = 0; rr < 32; ++rr) cs += ft[rr][tid];
    }
  }
  if (tid < 128) atomicAdd(&sv[tid], cs);
  if (tid < NCAT) blkcnt[blockIdx.x * NCAT + tid] = hl[tid];
  if (PART) {
    float* gp = Gdst + (size_t)blockIdx.x * 16384;
    #pragma unroll
    for (int a = 0; a < 4; ++a) {
      float4 v = make_float4(acc[a][0], acc[a][1], acc[a][2], acc[a][3]);
      *(float4*)&gp[(ty * 4 + a) * 128 + tx * 4] = v;
    }
  } else {
    #pragma unroll
    for (int a = 0; a < 4; ++a)
      #pragma unroll
      for (int b = 0; b < 4; ++b)
        atomicAdd(&Gdst[(ty * 4 + a) * 128 + tx * 4 + b], acc[a][b]);
  }
}

// K1b: reduce 256 partials -> G.
__global__ __launch_bounds__(64) void k_reduce(
    const float* __restrict__ Gpart, float* __restrict__ G)
{
  const int e = blockIdx.x * 64 + threadIdx.x;
  float s = 0.f;
  #pragma unroll 8
  for (int p = 0; p < 256; ++p) s += Gpart[(size_t)p * 16384 + e];
  G[e] = s;
}

// ---------------------------------------------------------------------------
// K1w: pre-swizzle W1 into bf16 MFMA B-fragment layout.
// Wlb[cat][frag_id=ks*8+ct][lane][j] = bf16(W1[32ks+8*(lane>>4)+j][cat*128+16ct+(lane&15)])
// grid 64 = 16 cats x 4 parts; 256 threads; 2 entries/thread.
// ---------------------------------------------------------------------------
__global__ __launch_bounds__(256) void k_wswz(
    const float* __restrict__ W1, unsigned short* __restrict__ Wlb)
{
  const int cat = blockIdx.x >> 2, part = blockIdx.x & 3;
  for (int i = 0; i < 2; ++i) {
    const int e = part * 512 + threadIdx.x + i * 256;   // 0..2047 per cat
    const int fid = e >> 6, l = e & 63;
    const int ks = fid >> 3, ct = fid & 7;
    const int kb = 32 * ks + 8 * (l >> 4);
    const int c = cat * 128 + 16 * ct + (l & 15);
    unsigned short v[8];
    #pragma unroll
    for (int j = 0; j < 8; ++j)
      v[j] = f2bf(W1[(size_t)(kb + j) * 2048 + c]);
    uint4 pk;
    pk.x = (unsigned)v[0] | ((unsigned)v[1] << 16);
    pk.y = (unsigned)v[2] | ((unsigned)v[3] << 16);
    pk.z = (unsigned)v[4] | ((unsigned)v[5] << 16);
    pk.w = (unsigned)v[6] | ((unsigned)v[7] << 16);
    *(uint4*)(Wlb + ((size_t)(cat * 32 + fid) * 64 + l) * 8) = pk;
  }
}

// ---------------------------------------------------------------------------
// K1c: prefix sums over blkcnt -> offs[block][cat], counts[cat]. 1 block.
// ---------------------------------------------------------------------------
__global__ __launch_bounds__(256) void k_prefix(
    const int* __restrict__ blkcnt, int* __restrict__ offs,
    int* __restrict__ counts)
{
  __shared__ int ps[16][16];
  __shared__ int ps2[16][16];
  __shared__ int tot[16];
  __shared__ int catbase[16];
  const int tid = threadIdx.x;
  const int part = tid >> 4, cat = tid & 15;
  int v[16];
  int s = 0;
  #pragma unroll
  for (int i = 0; i < 16; ++i) {
    v[i] = s;
    s += blkcnt[(part * 16 + i) * 16 + cat];
  }
  ps[part][cat] = s;
  __syncthreads();
  if (part == 0) {
    int acc = 0;
    #pragma unroll
    for (int p = 0; p < 16; ++p) { ps2[p][cat] = acc; acc += ps[p][cat]; }
    tot[cat] = acc;
    counts[cat] = acc;
  }
  __syncthreads();
  if (tid == 0) {
    int acc = 0;
    #pragma unroll
    for (int c = 0; c < 16; ++c) { catbase[c] = acc; acc += tot[c]; }
  }
  __syncthreads();
  const int base = catbase[cat] + ps2[part][cat];
  #pragma unroll
  for (int i = 0; i < 16; ++i)
    offs[(part * 16 + i) * 16 + cat] = base + v[i];
}

// ---------------------------------------------------------------------------
// K3: compact row indices by category — atomic-free, deterministic.
// ---------------------------------------------------------------------------
__global__ __launch_bounds__(256) void k_scatter(
    const int* __restrict__ lab, const int* __restrict__ offs,
    int* __restrict__ rowidx)
{
  __shared__ int wc[4][NCAT];
  const int tid = threadIdx.x;
  const int wid = tid >> 6, lane = tid & 63;
  const int n = blockIdx.x * 256 + tid;
  const int c = lab[n];
  const unsigned long long lanebit = 1ull << lane;
  int myrank = 0;
  #pragma unroll
  for (int cc = 0; cc < NCAT; ++cc) {
    unsigned long long m = __ballot(c == cc);
    if (lane == 0) wc[wid][cc] = (int)__popcll(m);
    if (c == cc) myrank = (int)__popcll(m & (lanebit - 1));
  }
  __syncthreads();
  int base = 0;
  #pragma unroll
  for (int w = 0; w < 4; ++w)
    if (w < wid) base += wc[w][c];
  rowidx[offs[blockIdx.x * NCAT + c] + base + myrank] = n;
}

// ---------------------------------------------------------------------------
// K2: BN parameters from Gram matrix.
// ---------------------------------------------------------------------------
__global__ __launch_bounds__(256) void k_params(
    const float* __restrict__ G, const float* __restrict__ sv,
    const float* __restrict__ W1, const float* __restrict__ gamma,
    const float* __restrict__ beta, float* __restrict__ scale,
    float* __restrict__ shiftv)
{
  __shared__ float Gl[128][133];
  __shared__ float Wl[128][16];
  __shared__ float redq[16][16];
  __shared__ float redm[16][16];
  const int tid = threadIdx.x;
  const int jb = blockIdx.x * 16;
  for (int i = tid; i < 16384; i += 256) Gl[i >> 7][i & 127] = G[i];
  for (int i = tid; i < 2048; i += 256) {
    int k = i >> 4, col = i & 15;
    Wl[k][col] = W1[(size_t)k * 2048 + jb + col];
  }
  __syncthreads();
  const int col = tid & 15, part = tid >> 4;
  float msq = 0.f, mean = 0.f;
  for (int ii = 0; ii < 8; ++ii) {
    const int i = part * 8 + ii;
    const float wi = Wl[i][col];
    float inner = 0.f;
    #pragma unroll 8
    for (int k = 0; k < 128; ++k) inner = fmaf(Gl[i][k], Wl[k][col], inner);
    msq = fmaf(wi, inner, msq);
  }
  #pragma unroll
  for (int kk = 0; kk < 8; ++kk) {
    const int k = part * 8 + kk;
    mean = fmaf(sv[k], Wl[k][col], mean);
  }
  redq[part][col] = msq;
  redm[part][col] = mean;
  __syncthreads();
  if (tid < 16) {
    float q = 0.f, m = 0.f;
    #pragma unroll
    for (int p = 0; p < 16; ++p) { q += redq[p][tid]; m += redm[p][tid]; }
    m *= (1.f / 65536.f);
    q *= (1.f / 65536.f);
    float var = q - m * m;
    float sc = gamma[jb + tid] * rsqrtf(var + 1e-5f);
    scale[jb + tid] = sc;
    shiftv[jb + tid] = beta[jb + tid] - m * sc;
  }
}

// ---------------------------------------------------------------------------
// K4: MFMA main pass. grid = 16 cat x BCAT; 256 thr = 4 waves.
// Per wave-iter: 16 rows x 128 cols, K=128 via 32x mfma_f32_16x16x32_bf16.
// A-frags straight from global F (lane l: row rows16[l&15], k=8*(l>>4)+j).
// B-frags from pre-swizzled LDS copy (32 KB). C/D: col=lane&15,
// row=(lane>>4)*4+reg (verified layout). Epilogue: BN+leaky+W2 in-reg,
// 16-lane butterfly, log-softmax, segment-only stores (out pre-zeroed).
// ---------------------------------------------------------------------------
__global__ __launch_bounds__(256) void k_main(
    const float* __restrict__ F, const unsigned short* __restrict__ Wlb,
    const float* __restrict__ W2, const float* __restrict__ bias,
    const float* __restrict__ scale, const float* __restrict__ shiftv,
    const int* __restrict__ counts, const int* __restrict__ rowidx,
    float* __restrict__ out)
{
  __shared__ uint4 WlU[2048];      // 32 KB bf16 frag-layout W tile
  __shared__ float W2l[768];
  __shared__ float scl[128], shl[128];
  const int tid = threadIdx.x;
  const int cat = (int)blockIdx.x >> 5;
  const int blk = (int)blockIdx.x & (BCAT - 1);
  int off = 0, cnt = 0;
  #pragma unroll
  for (int t = 0; t < NCAT; ++t) {
    int cv = counts[t];
    if (t < cat) off += cv;
    if (t == cat) cnt = cv;
  }
  {
    const uint4* src = (const uint4*)(Wlb + (size_t)cat * 16384);
    for (int i = tid; i < 2048; i += 256) WlU[i] = src[i];
    for (int i = tid; i < 768; i += 256) W2l[i] = W2[cat * 768 + i];
    if (tid < 128) { scl[tid] = scale[cat * 128 + tid]; shl[tid] = shiftv[cat * 128 + tid]; }
  }
  const int wid = tid >> 6, lane = tid & 63;
  const int lrow = lane & 15, lhi = lane >> 4;
  const int shc = c_shift[cat], lnc = c_len[cat];
  float bi[6];
  #pragma unroll
  for (int s = 0; s < 6; ++s) bi[s] = bias[s];
  __syncthreads();

  const unsigned short* wl = (const unsigned short*)WlU;
  const int chunk = (cnt + BCAT - 1) / BCAT;
  const int start = off + blk * chunk;
  const int end = min(start + chunk, off + cnt);

  for (int q0 = start; q0 < end; q0 += 64) {
    const int base = q0 + wid * 16;
    const int rA = rowidx[min(base + lrow, end - 1)];
    const float* fp = F + (size_t)rA * 128 + lhi * 8;

    float4v acc[8];
    #pragma unroll
    for (int ct = 0; ct < 8; ++ct) acc[ct] = (float4v){0.f, 0.f, 0.f, 0.f};

    #pragma unroll
    for (int ks = 0; ks < 4; ++ks) {
      float4 a0 = *(const float4*)(fp + ks * 32);
      float4 a1 = *(const float4*)(fp + ks * 32 + 4);
      short8v av;
      av[0] = (short)f2bf(a0.x); av[1] = (short)f2bf(a0.y);
      av[2] = (short)f2bf(a0.z); av[3] = (short)f2bf(a0.w);
      av[4] = (short)f2bf(a1.x); av[5] = (short)f2bf(a1.y);
      av[6] = (short)f2bf(a1.z); av[7] = (short)f2bf(a1.w);
      #pragma unroll
      for (int ct = 0; ct < 8; ++ct) {
        short8v bv = *(const short8v*)(wl + ((ks * 8 + ct) * 64 + lane) * 8);
        acc[ct] = __builtin_amdgcn_mfma_f32_16x16x32_bf16(av, bv, acc[ct], 0, 0, 0);
      }
    }

    // epilogue: BN + leaky + W2 partials (lane cols: 16ct + lrow; rows 4*lhi+j)
    float p[4][6];
    #pragma unroll
    for (int j = 0; j < 4; ++j)
      #pragma unroll
      for (int s = 0; s < 6; ++s) p[j][s] = 0.f;
    #pragma unroll
    for (int ct = 0; ct < 8; ++ct) {
      const int c = ct * 16 + lrow;
      const float s_ = scl[c], h_ = shl[c];
      float w2v[6];
      #pragma unroll
      for (int s = 0; s < 6; ++s) w2v[s] = W2l[c * 6 + s];
      #pragma unroll
      for (int j = 0; j < 4; ++j) {
        float a = acc[ct][j] * s_ + h_;
        a = (a >= 0.f) ? a : 0.2f * a;
        #pragma unroll
        for (int s = 0; s < 6; ++s) p[j][s] = fmaf(a, w2v[s], p[j][s]);
      }
    }
    // reduce over the 16-lane group (sum over cols)
    #pragma unroll
    for (int dm = 1; dm < 16; dm <<= 1) {
      #pragma unroll
      for (int j = 0; j < 4; ++j)
        #pragma unroll
        for (int s = 0; s < 6; ++s) p[j][s] += __shfl_xor(p[j][s], dm);
    }
    // lane lrow handles (row = 4*lhi + (lrow&3), s-slots lrow>>2 and +4)
    const int jj = lrow & 3, sb = lrow >> 2;
    const int rG = rowidx[min(base + 4 * lhi + jj, end - 1)];
    float pj[6];
    #pragma unroll
    for (int s = 0; s < 6; ++s) pj[s] = p[jj][s] + bi[s];
    float mx = fmaxf(fmaxf(fmaxf(pj[0], pj[1]), fmaxf(pj[2], pj[3])), fmaxf(pj[4], pj[5]));
    float e = __expf(pj[0] - mx) + __expf(pj[1] - mx) + __expf(pj[2] - mx)
            + __expf(pj[3] - mx) + __expf(pj[4] - mx) + __expf(pj[5] - mx);
    float lse = mx + __logf(e);
    if (sb < lnc)      out[(size_t)rG * 54 + shc + sb]     = pj[sb] - lse;
    if (sb + 4 < lnc)  out[(size_t)rG * 54 + shc + sb + 4] = pj[sb + 4] - lse;
  }
}

// ---------------------------------------------------------------------------
// Host launcher
// ---------------------------------------------------------------------------
extern "C" void kernel_launch(void* const* d_in, const int* in_sizes, int n_in,
                              void* d_out, int out_size, void* d_ws, size_t ws_size,
                              hipStream_t stream) {
  const float* F     = (const float*)d_in[0];
  const float* W1    = (const float*)d_in[1];
  const float* gamma = (const float*)d_in[2];
  const float* beta  = (const float*)d_in[3];
  const float* W2    = (const float*)d_in[4];
  const float* bias  = (const float*)d_in[5];
  const int*   lab   = (const int*)d_in[6];
  float* out = (float*)d_out;

  char* ws = (char*)d_ws;
  float* sv      = (float*)(ws + 0);
  int*   counts  = (int*)(ws + 512);
  int*   blkcnt  = (int*)(ws + 576);
  int*   offs    = (int*)(ws + 16960);
  float* scale   = (float*)(ws + 33344);
  float* shiftv  = (float*)(ws + 41536);
  float* G       = (float*)(ws + 49728);
  int*   rowidx  = (int*)(ws + 115264);
  float* Gpart   = (float*)(ws + 377408);
  unsigned short* Wlb = (unsigned short*)(ws + 377408);  // reuses Gpart after k_reduce

  hipMemsetAsync(d_out, 0, (size_t)out_size * 4, stream);

  const size_t need = 377408 + (size_t)256 * 16384 * 4;  // ~17.2 MB
  if (ws_size >= need) {
    hipMemsetAsync(d_ws, 0, 576, stream);    // sv (+counts)
    hipLaunchKernelGGL(k_stats_t<true>, dim3(256), dim3(1024), 0, stream,
                       F, lab, Gpart, sv, blkcnt);
    hipLaunchKernelGGL(k_reduce, dim3(256), dim3(64), 0, stream, Gpart, G);
  } else {
    hipMemsetAsync(d_ws, 0, 115264, stream); // also zero G for atomics
    hipLaunchKernelGGL(k_stats_t<false>, dim3(256), dim3(1024), 0, stream,
                       F, lab, G, sv, blkcnt);
  }
  hipLaunchKernelGGL(k_wswz, dim3(64), dim3(256), 0, stream, W1, Wlb);
  hipLaunchKernelGGL(k_prefix, dim3(1), dim3(256), 0, stream, blkcnt, offs, counts);
  hipLaunchKernelGGL(k_scatter, dim3(256), dim3(256), 0, stream, lab, offs, rowidx);
  hipLaunchKernelGGL(k_params, dim3(128), dim3(256), 0, stream, G, sv, W1, gamma, beta, scale, shiftv);
  hipLaunchKernelGGL(k_main, dim3(NCAT * BCAT), dim3(256), 0, stream, F, Wlb, W2, bias,
                     scale, shiftv, counts, rowidx, out);
}

// Round 5
// 101.351 us; speedup vs baseline: 4.8478x; 1.1453x over previous
//
#include <hip/hip_runtime.h>

#define NROWS 65536
#define NCAT 16
#define BCAT 64   // blocks per category in k_main

typedef __attribute__((ext_vector_type(8))) short short8v;
typedef __attribute__((ext_vector_type(4))) float float4v;
typedef __attribute__((ext_vector_type(16))) float f32x16;

__constant__ int c_shift[NCAT] = {0,4,6,8,12,16,19,22,24,28,34,36,42,45,48,51};
__constant__ int c_len[NCAT]   = {4,2,2,4,4,3,3,2,4,6,2,6,3,3,3,3};

// ws layout (bytes):
//   sv      @ 0       (128 f32)
//   counts  @ 512     (16 i32)
//   blkcnt  @ 576     (256*16 i32)  -> 16960
//   offs    @ 16960   (256*16 i32)  -> 33344
//   scale   @ 33344   (2048 f32)    -> 41536
//   shiftv  @ 41536   (2048 f32)    -> 49728
//   G       @ 49728   (16384 f32)   -> 115264
//   rowidx  @ 115264  (65536 i32)   -> 377408
//   Gpart   @ 377408  (256*16384 f32 = 16 MB)  [k_stats -> k_reduce]
//   Wlb     @ 377408  (512 KB) [k_wswz AFTER k_reduce reuses dead Gpart region]

static inline __device__ unsigned short f2bf(float x) {
  union { float f; unsigned int u; } v; v.f = x;
  unsigned int r = v.u + 0x7fffu + ((v.u >> 16) & 1u);   // RNE
  return (unsigned short)(r >> 16);
}

// ---------------------------------------------------------------------------
// K1: MFMA Gram. 256 blocks x 1024 thr (16 waves). Block = 256 rows.
// Wave w -> C tile (wi=w>>2, wj=w&3) of 32x32; K accumulated over 256 rows
// via 16x mfma_f32_32x32x16_bf16. A/B frags gathered DIRECTLY from global F
// (2x128B segments per load, L1-amplified). sv rides on wj==0 A-loads (f32).
// C/D layout (verified m74/m101): col=lane&31, row=(reg&3)+8*(reg>>2)+4*(l>>5).
// ---------------------------------------------------------------------------
template<bool PART>
__global__ __launch_bounds__(1024) void k_stats_m(
    const float* __restrict__ F, const int* __restrict__ lab,
    float* __restrict__ Gdst, float* __restrict__ sv, int* __restrict__ blkcnt)
{
  __shared__ int hl[NCAT];
  const int tid = threadIdx.x;
  if (tid < NCAT) hl[tid] = 0;
  __syncthreads();
  const int rowbase = blockIdx.x * 256;
  if (tid < 256) atomicAdd(&hl[lab[rowbase + tid]], 1);

  const int wid = tid >> 6, lane = tid & 63;
  const int wi = wid >> 2, wj = wid & 3;
  const int i0 = wi * 32, j0 = wj * 32;
  const int lr = lane & 31, lh = lane >> 5;

  f32x16 acc;
  #pragma unroll
  for (int e = 0; e < 16; ++e) acc[e] = 0.f;
  float svacc = 0.f;

  for (int ch = 0; ch < 8; ++ch) {
    #pragma unroll
    for (int h = 0; h < 2; ++h) {
      const int rbase = rowbase + ch * 32 + 16 * h + 8 * lh;
      float fa[8], fb[8];
      #pragma unroll
      for (int j = 0; j < 8; ++j) {
        const float* rp = F + (size_t)(rbase + j) * 128;
        fa[j] = rp[i0 + lr];
        fb[j] = rp[j0 + lr];
      }
      if (wj == 0) {
        #pragma unroll
        for (int j = 0; j < 8; ++j) svacc += fa[j];
      }
      short8v av, bv;
      #pragma unroll
      for (int j = 0; j < 8; ++j) {
        av[j] = (short)f2bf(fa[j]);
        bv[j] = (short)f2bf(fb[j]);
      }
      acc = __builtin_amdgcn_mfma_f32_32x32x16_bf16(av, bv, acc, 0, 0, 0);
    }
  }

  if (wj == 0) {
    svacc += __shfl_xor(svacc, 32);
    if (lane < 32) atomicAdd(&sv[i0 + lr], svacc);
  }
  __syncthreads();
  if (tid < NCAT) blkcnt[blockIdx.x * NCAT + tid] = hl[tid];

  if (PART) {
    float* gp = Gdst + (size_t)blockIdx.x * 16384;
    #pragma unroll
    for (int reg = 0; reg < 16; ++reg) {
      const int row = (reg & 3) + 8 * (reg >> 2) + 4 * lh;
      gp[(i0 + row) * 128 + j0 + lr] = acc[reg];
    }
  } else {
    #pragma unroll
    for (int reg = 0; reg < 16; ++reg) {
      const int row = (reg & 3) + 8 * (reg >> 2) + 4 * lh;
      atomicAdd(&Gdst[(i0 + row) * 128 + j0 + lr], acc[reg]);
    }
  }
}

// K1b: reduce 256 partials -> G.
__global__ __launch_bounds__(64) void k_reduce(
    const float* __restrict__ Gpart, float* __restrict__ G)
{
  const int e = blockIdx.x * 64 + threadIdx.x;
  float s = 0.f;
  #pragma unroll 8
  for (int p = 0; p < 256; ++p) s += Gpart[(size_t)p * 16384 + e];
  G[e] = s;
}

// ---------------------------------------------------------------------------
// K1w: pre-swizzle W1 into bf16 MFMA B-fragment layout.
// Wlb[cat][fid=ks*8+ct][lane][j] = bf16(W1[32ks+8*(l>>4)+j][cat*128+16ct+(l&15)])
// ---------------------------------------------------------------------------
__global__ __launch_bounds__(256) void k_wswz(
    const float* __restrict__ W1, unsigned short* __restrict__ Wlb)
{
  const int cat = blockIdx.x >> 2, part = blockIdx.x & 3;
  for (int i = 0; i < 2; ++i) {
    const int e = part * 512 + threadIdx.x + i * 256;
    const int fid = e >> 6, l = e & 63;
    const int ks = fid >> 3, ct = fid & 7;
    const int kb = 32 * ks + 8 * (l >> 4);
    const int c = cat * 128 + 16 * ct + (l & 15);
    unsigned short v[8];
    #pragma unroll
    for (int j = 0; j < 8; ++j)
      v[j] = f2bf(W1[(size_t)(kb + j) * 2048 + c]);
    uint4 pk;
    pk.x = (unsigned)v[0] | ((unsigned)v[1] << 16);
    pk.y = (unsigned)v[2] | ((unsigned)v[3] << 16);
    pk.z = (unsigned)v[4] | ((unsigned)v[5] << 16);
    pk.w = (unsigned)v[6] | ((unsigned)v[7] << 16);
    *(uint4*)(Wlb + ((size_t)(cat * 32 + fid) * 64 + l) * 8) = pk;
  }
}

// ---------------------------------------------------------------------------
// K1c: prefix sums over blkcnt -> offs[block][cat], counts[cat]. 1 block.
// ---------------------------------------------------------------------------
__global__ __launch_bounds__(256) void k_prefix(
    const int* __restrict__ blkcnt, int* __restrict__ offs,
    int* __restrict__ counts)
{
  __shared__ int ps[16][16];
  __shared__ int ps2[16][16];
  __shared__ int tot[16];
  __shared__ int catbase[16];
  const int tid = threadIdx.x;
  const int part = tid >> 4, cat = tid & 15;
  int v[16];
  int s = 0;
  #pragma unroll
  for (int i = 0; i < 16; ++i) {
    v[i] = s;
    s += blkcnt[(part * 16 + i) * 16 + cat];
  }
  ps[part][cat] = s;
  __syncthreads();
  if (part == 0) {
    int acc = 0;
    #pragma unroll
    for (int p = 0; p < 16; ++p) { ps2[p][cat] = acc; acc += ps[p][cat]; }
    tot[cat] = acc;
    counts[cat] = acc;
  }
  __syncthreads();
  if (tid == 0) {
    int acc = 0;
    #pragma unroll
    for (int c = 0; c < 16; ++c) { catbase[c] = acc; acc += tot[c]; }
  }
  __syncthreads();
  const int base = catbase[cat] + ps2[part][cat];
  #pragma unroll
  for (int i = 0; i < 16; ++i)
    offs[(part * 16 + i) * 16 + cat] = base + v[i];
}

// ---------------------------------------------------------------------------
// K3: compact row indices by category — atomic-free, deterministic.
// ---------------------------------------------------------------------------
__global__ __launch_bounds__(256) void k_scatter(
    const int* __restrict__ lab, const int* __restrict__ offs,
    int* __restrict__ rowidx)
{
  __shared__ int wc[4][NCAT];
  const int tid = threadIdx.x;
  const int wid = tid >> 6, lane = tid & 63;
  const int n = blockIdx.x * 256 + tid;
  const int c = lab[n];
  const unsigned long long lanebit = 1ull << lane;
  int myrank = 0;
  #pragma unroll
  for (int cc = 0; cc < NCAT; ++cc) {
    unsigned long long m = __ballot(c == cc);
    if (lane == 0) wc[wid][cc] = (int)__popcll(m);
    if (c == cc) myrank = (int)__popcll(m & (lanebit - 1));
  }
  __syncthreads();
  int base = 0;
  #pragma unroll
  for (int w = 0; w < 4; ++w)
    if (w < wid) base += wc[w][c];
  rowidx[offs[blockIdx.x * NCAT + c] + base + myrank] = n;
}

// ---------------------------------------------------------------------------
// K2: BN parameters from Gram matrix.
// ---------------------------------------------------------------------------
__global__ __launch_bounds__(256) void k_params(
    const float* __restrict__ G, const float* __restrict__ sv,
    const float* __restrict__ W1, const float* __restrict__ gamma,
    const float* __restrict__ beta, float* __restrict__ scale,
    float* __restrict__ shiftv)
{
  __shared__ float Gl[128][133];
  __shared__ float Wl[128][16];
  __shared__ float redq[16][16];
  __shared__ float redm[16][16];
  const int tid = threadIdx.x;
  const int jb = blockIdx.x * 16;
  for (int i = tid; i < 16384; i += 256) Gl[i >> 7][i & 127] = G[i];
  for (int i = tid; i < 2048; i += 256) {
    int k = i >> 4, col = i & 15;
    Wl[k][col] = W1[(size_t)k * 2048 + jb + col];
  }
  __syncthreads();
  const int col = tid & 15, part = tid >> 4;
  float msq = 0.f, mean = 0.f;
  for (int ii = 0; ii < 8; ++ii) {
    const int i = part * 8 + ii;
    const float wi = Wl[i][col];
    float inner = 0.f;
    #pragma unroll 8
    for (int k = 0; k < 128; ++k) inner = fmaf(Gl[i][k], Wl[k][col], inner);
    msq = fmaf(wi, inner, msq);
  }
  #pragma unroll
  for (int kk = 0; kk < 8; ++kk) {
    const int k = part * 8 + kk;
    mean = fmaf(sv[k], Wl[k][col], mean);
  }
  redq[part][col] = msq;
  redm[part][col] = mean;
  __syncthreads();
  if (tid < 16) {
    float q = 0.f, m = 0.f;
    #pragma unroll
    for (int p = 0; p < 16; ++p) { q += redq[p][tid]; m += redm[p][tid]; }
    m *= (1.f / 65536.f);
    q *= (1.f / 65536.f);
    float var = q - m * m;
    float sc = gamma[jb + tid] * rsqrtf(var + 1e-5f);
    scale[jb + tid] = sc;
    shiftv[jb + tid] = beta[jb + tid] - m * sc;
  }
}

// ---------------------------------------------------------------------------
// K4: MFMA main pass. grid = 16 cat x BCAT(64); 256 thr = 4 waves; ~1 iter/wave.
// B-frags straight from GLOBAL Wlb (1KB coalesced, L1/L2-hot). A-frags from
// global F. Epilogue: BN+leaky+W2 in-reg; reduce-scatter butterfly (30 shfl):
// lvl1/2 split by j-parity so lane ends with j=lrow&3, lvl3/4 all-reduce.
// ---------------------------------------------------------------------------
__global__ __launch_bounds__(256) void k_main(
    const float* __restrict__ F, const unsigned short* __restrict__ Wlb,
    const float* __restrict__ W2, const float* __restrict__ bias,
    const float* __restrict__ scale, const float* __restrict__ shiftv,
    const int* __restrict__ counts, const int* __restrict__ rowidx,
    float* __restrict__ out)
{
  __shared__ float W2l[768];
  const int tid = threadIdx.x;
  const int cat = (int)blockIdx.x >> 6;
  const int blk = (int)blockIdx.x & (BCAT - 1);
  int off = 0, cnt = 0;
  #pragma unroll
  for (int t = 0; t < NCAT; ++t) {
    int cv = counts[t];
    if (t < cat) off += cv;
    if (t == cat) cnt = cv;
  }
  for (int i = tid; i < 768; i += 256) W2l[i] = W2[cat * 768 + i];
  const int wid = tid >> 6, lane = tid & 63;
  const int lrow = lane & 15, lhi = lane >> 4;
  const int shc = c_shift[cat], lnc = c_len[cat];
  float bi[6];
  #pragma unroll
  for (int s = 0; s < 6; ++s) bi[s] = bias[s];
  float sc_r[8], sh_r[8];
  #pragma unroll
  for (int ct = 0; ct < 8; ++ct) {
    sc_r[ct] = scale[cat * 128 + ct * 16 + lrow];
    sh_r[ct] = shiftv[cat * 128 + ct * 16 + lrow];
  }
  __syncthreads();

  const unsigned short* wbase = Wlb + (size_t)cat * 16384;
  const int chunk = (cnt + BCAT - 1) / BCAT;
  const int start = off + blk * chunk;
  const int end = min(start + chunk, off + cnt);

  for (int q0 = start; q0 < end; q0 += 64) {
    const int base = q0 + wid * 16;
    const int rA = rowidx[min(base + lrow, end - 1)];
    const float* fp = F + (size_t)rA * 128 + lhi * 8;

    float4v acc[8];
    #pragma unroll
    for (int ct = 0; ct < 8; ++ct) acc[ct] = (float4v){0.f, 0.f, 0.f, 0.f};

    #pragma unroll
    for (int ks = 0; ks < 4; ++ks) {
      float4 a0 = *(const float4*)(fp + ks * 32);
      float4 a1 = *(const float4*)(fp + ks * 32 + 4);
      short8v av;
      av[0] = (short)f2bf(a0.x); av[1] = (short)f2bf(a0.y);
      av[2] = (short)f2bf(a0.z); av[3] = (short)f2bf(a0.w);
      av[4] = (short)f2bf(a1.x); av[5] = (short)f2bf(a1.y);
      av[6] = (short)f2bf(a1.z); av[7] = (short)f2bf(a1.w);
      #pragma unroll
      for (int ct = 0; ct < 8; ++ct) {
        short8v bv = *(const short8v*)(wbase + ((ks * 8 + ct) * 64 + lane) * 8);
        acc[ct] = __builtin_amdgcn_mfma_f32_16x16x32_bf16(av, bv, acc[ct], 0, 0, 0);
      }
    }

    // BN + leaky + W2 partials (lane col c = 16ct+lrow; rows 4*lhi+j)
    float p[4][6];
    #pragma unroll
    for (int j = 0; j < 4; ++j)
      #pragma unroll
      for (int s = 0; s < 6; ++s) p[j][s] = 0.f;
    #pragma unroll
    for (int ct = 0; ct < 8; ++ct) {
      const int c = ct * 16 + lrow;
      const float s_ = sc_r[ct], h_ = sh_r[ct];
      float w2v[6];
      #pragma unroll
      for (int s = 0; s < 6; ++s) w2v[s] = W2l[c * 6 + s];
      #pragma unroll
      for (int j = 0; j < 4; ++j) {
        float a = acc[ct][j] * s_ + h_;
        a = (a >= 0.f) ? a : 0.2f * a;
        #pragma unroll
        for (int s = 0; s < 6; ++s) p[j][s] = fmaf(a, w2v[s], p[j][s]);
      }
    }
    // reduce-scatter over the 16-lane group: lvl1/2 keep j == lrow&3
    const bool b1 = (lrow & 1) != 0;
    const bool b2 = (lrow & 2) != 0;
    float q[2][6], r[6];
    #pragma unroll
    for (int t = 0; t < 2; ++t)
      #pragma unroll
      for (int s = 0; s < 6; ++s) {
        float snd = b1 ? p[2 * t][s] : p[2 * t + 1][s];
        float kp  = b1 ? p[2 * t + 1][s] : p[2 * t][s];
        q[t][s] = kp + __shfl_xor(snd, 1);
      }
    #pragma unroll
    for (int s = 0; s < 6; ++s) {
      float snd = b2 ? q[0][s] : q[1][s];
      float kp  = b2 ? q[1][s] : q[0][s];
      r[s] = kp + __shfl_xor(snd, 2);
    }
    #pragma unroll
    for (int s = 0; s < 6; ++s) r[s] += __shfl_xor(r[s], 4);
    #pragma unroll
    for (int s = 0; s < 6; ++s) r[s] += __shfl_xor(r[s], 8);

    const int jj = lrow & 3, sb = lrow >> 2;
    const int rG = rowidx[min(base + 4 * lhi + jj, end - 1)];
    float pj[6];
    #pragma unroll
    for (int s = 0; s < 6; ++s) pj[s] = r[s] + bi[s];
    float mx = fmaxf(fmaxf(fmaxf(pj[0], pj[1]), fmaxf(pj[2], pj[3])), fmaxf(pj[4], pj[5]));
    float e = __expf(pj[0] - mx) + __expf(pj[1] - mx) + __expf(pj[2] - mx)
            + __expf(pj[3] - mx) + __expf(pj[4] - mx) + __expf(pj[5] - mx);
    float lse = mx + __logf(e);
    if (sb < lnc)      out[(size_t)rG * 54 + shc + sb]     = pj[sb] - lse;
    if (sb + 4 < lnc)  out[(size_t)rG * 54 + shc + sb + 4] = pj[sb + 4] - lse;
  }
}

// ---------------------------------------------------------------------------
// Host launcher
// ---------------------------------------------------------------------------
extern "C" void kernel_launch(void* const* d_in, const int* in_sizes, int n_in,
                              void* d_out, int out_size, void* d_ws, size_t ws_size,
                              hipStream_t stream) {
  const float* F     = (const float*)d_in[0];
  const float* W1    = (const float*)d_in[1];
  const float* gamma = (const float*)d_in[2];
  const float* beta  = (const float*)d_in[3];
  const float* W2    = (const float*)d_in[4];
  const float* bias  = (const float*)d_in[5];
  const int*   lab   = (const int*)d_in[6];
  float* out = (float*)d_out;

  char* ws = (char*)d_ws;
  float* sv      = (float*)(ws + 0);
  int*   counts  = (int*)(ws + 512);
  int*   blkcnt  = (int*)(ws + 576);
  int*   offs    = (int*)(ws + 16960);
  float* scale   = (float*)(ws + 33344);
  float* shiftv  = (float*)(ws + 41536);
  float* G       = (float*)(ws + 49728);
  int*   rowidx  = (int*)(ws + 115264);
  float* Gpart   = (float*)(ws + 377408);
  unsigned short* Wlb = (unsigned short*)(ws + 377408);  // reuses Gpart after k_reduce

  hipMemsetAsync(d_out, 0, (size_t)out_size * 4, stream);

  const size_t need = 377408 + (size_t)256 * 16384 * 4;  // ~17.2 MB
  if (ws_size >= need) {
    hipMemsetAsync(d_ws, 0, 576, stream);    // sv + counts
    hipLaunchKernelGGL(k_stats_m<true>, dim3(256), dim3(1024), 0, stream,
                       F, lab, Gpart, sv, blkcnt);
    hipLaunchKernelGGL(k_reduce, dim3(256), dim3(64), 0, stream, Gpart, G);
  } else {
    hipMemsetAsync(d_ws, 0, 115264, stream); // also zero G for atomics
    hipLaunchKernelGGL(k_stats_m<false>, dim3(256), dim3(1024), 0, stream,
                       F, lab, G, sv, blkcnt);
  }
  hipLaunchKernelGGL(k_wswz, dim3(64), dim3(256), 0, stream, W1, Wlb);
  hipLaunchKernelGGL(k_prefix, dim3(1), dim3(256), 0, stream, blkcnt, offs, counts);
  hipLaunchKernelGGL(k_scatter, dim3(256), dim3(256), 0, stream, lab, offs, rowidx);
  hipLaunchKernelGGL(k_params, dim3(128), dim3(256), 0, stream, G, sv, W1, gamma, beta, scale, shiftv);
  hipLaunchKernelGGL(k_main, dim3(NCAT * BCAT), dim3(256), 0, stream, F, Wlb, W2, bias,
                     scale, shiftv, counts, rowidx, out);
}